// Round 22
// baseline (250.549 us; speedup 1.0000x reference)
//
#include <hip/hip_runtime.h>
#include <hip/hip_bf16.h>
#include <math.h>

// Problem constants
#define T_ 4
#define N_ 16
#define F_ 6
#define L_ 1024
#define A_ 21
#define K_ 20
#define U_ 256
#define LOUT 1005            // L - K + 1
#define NIMG 384             // T*N*F
#define SZ_S (T_*N_*U_)      // 16384
#define SZ_R (K_*A_*U_)      // 107520

// Packed-X geometry: row stride 24 shorts (48 B). For output row l, contraction
// slot c maps to tap=c/24, col=c%24 (independent of l). Valid slots 0..476 ->
// 15 K-steps of 32 (480); cols 21..23 zero in R.
#define XPR 24               // shorts per packed row
#define XROWS 1056           // padded rows per image
#define NSTEP 15             // K-steps of 32 slots
#define XWCH 7               // private X chunks of 1 KB per wave (149 rows)

typedef __attribute__((ext_vector_type(8))) short short8;   // 8 bf16 (4 VGPR)
typedef __attribute__((ext_vector_type(4))) float f32x4;    // 4 f32 acc
typedef __attribute__((ext_vector_type(4))) unsigned int uint4v;

__device__ __forceinline__ unsigned short f2bf(float f) {
  unsigned int u = __float_as_uint(f);
  u += 0x7FFFu + ((u >> 16) & 1u);   // round to nearest even
  return (unsigned short)(u >> 16);
}

__device__ __forceinline__ void atomicMaxF(float* addr, float val) {
  if (val >= 0.f) atomicMax((int*)addr, __float_as_int(val));
  else            atomicMin((unsigned int*)addr, __float_as_uint(val));
}

// Async global->LDS, 16B per lane. LDS dest is wave-uniform base + lane*16.
__device__ __forceinline__ void gload_lds16(const void* g, void* l) {
  __builtin_amdgcn_global_load_lds(
      (const __attribute__((address_space(1))) void*)g,
      (__attribute__((address_space(3))) void*)l, 16, 0, 0);
}

// Merged pre-pass (single launch): S init, R (fp32 exact) -> d_out,
// Rt = bf16 R in slot order Rt[(s>>5)*(U*32) + u*32 + (s&31)] (pads zeroed),
// X fp32 -> packed bf16 Xp.
__global__ void xprep_kernel(const float* __restrict__ X,
                             const float* __restrict__ P_logit,
                             const float* __restrict__ Q,
                             float* __restrict__ out,
                             unsigned short* __restrict__ Rt,
                             unsigned int* __restrict__ Xp32) {
  int t = blockIdx.x * blockDim.x + threadIdx.x;
  if (t < SZ_S) out[t] = -INFINITY;            // S init for atomic max

  if (t < K_ * U_) {                           // R / Rt part
    int k = t / U_;
    int u = t - k * U_;
    const float* pl = P_logit + (size_t)k * A_ * U_ + u;
    float v[A_];
    float m = -INFINITY;
#pragma unroll
    for (int a = 0; a < A_; ++a) { v[a] = pl[(size_t)a * U_]; m = fmaxf(m, v[a]); }
    float s = 0.f;
#pragma unroll
    for (int a = 0; a < A_; ++a) { v[a] = expf(v[a] - m); s += v[a]; }
    float qs = 0.f;
#pragma unroll
    for (int a = 0; a < A_; ++a) qs += Q[a];
    float eps = qs * (1.0f / A_);
    float invs = 1.f / s;
    float* Rout = out + SZ_S;
#pragma unroll
    for (int a = 0; a < XPR; ++a) {
      unsigned short bv = 0;
      if (a < A_) {
        float r = logf(fmaxf(v[a] * invs / Q[a], eps));
        Rout[(size_t)(k * A_ + a) * U_ + u] = r;
        bv = f2bf(r);
      }
      int sl = k * XPR + a;
      Rt[(size_t)(sl >> 5) * (U_ * 32) + u * 32 + (sl & 31)] = bv;
    }
  }

  if (t < NIMG * XROWS * 12) {                 // X conversion part
    int w  = t % 12;
    int rl = t / 12;               // n*XROWS + row
    int row = rl % XROWS;
    int n   = rl / XROWS;
    int c0 = w * 2;
    float v0 = 0.f, v1 = 0.f;
    if (row < L_) {
      const float* xr = X + ((size_t)n * L_ + row) * A_;
      if (c0 < A_)     v0 = xr[c0];
      if (c0 + 1 < A_) v1 = xr[c0 + 1];
    }
    unsigned int o = (unsigned int)f2bf(v0) | ((unsigned int)f2bf(v1) << 16);
    Xp32[(size_t)rl * 12 + w] = o;
  }
}

// Conv as one GEMM: M=u (A=R slots), N=l (B=packed-X window), K=480 (15 steps).
// R22 = R21 (paced stores, 120.1 µs) + 3-IMAGES-PER-BLOCK persistence with the
// R20 dump-contention bug FIXED: grid = 2 u-halves x 128 = 256 blocks (1/CU);
// each block runs images {n0, n0+128, n0+256} through one continuous 12-tile
// store pipeline (one cold tile + one exposed tail drain per CU instead of
// three; R staged once per block). Cross-image t3 stores are clamped to a
// PER-WAVE-PRIVATE dump region (hash(block)*4+wid -> distinct 16 KB regions,
// distinct lines per lane) -- R20 used one shared 4 KB for all 768 blocks,
// which serialized on cross-XCD same-line stores (247 µs). Store groups paced
// at steps {1,2,4,5,7,9,10,12} (R21-proven). T14 reg-staged X, zero barriers
// after prologue, per-image S flush. 4 waves (2u x 2l), wave 64u x 128l.
__global__ __launch_bounds__(256, 1) void conv_kernel(
    const unsigned short* __restrict__ Xp,
    const unsigned short* __restrict__ Rt,
    float* __restrict__ out,
    float* __restrict__ dump) {
  __shared__ __align__(16) unsigned short lds_r[NSTEP * 4096];     // 120 KB
  __shared__ __align__(16) unsigned short lds_xp[4][XWCH * 512];   // 28 KB

  const int n0 = blockIdx.z;           // images n0, n0+128, n0+256
  const int u0 = blockIdx.x * 128;
  const int wid  = threadIdx.x >> 6;
  const int lane = threadIdx.x & 63;
  const int wl = wid >> 1;             // wave l position (0..1), 128 l each
  const int wu = wid & 1;              // wave u position (0..1), 64 u each

  const char* rsrc = (const char*)Rt + (size_t)u0 * 64;   // block's u-half
  char* xdst = (char*)&lds_xp[wid][0];
  // per-wave-private dump region (4096 floats = 16 KB); distinct per lane.
  float* wdump = dump +
      ((size_t)(((blockIdx.z * 2 + blockIdx.x) & 63) * 4 + wid)) * 4096 +
      lane * 64;

  // ---- prologue: ALL of R (30 chunks/wave, shared) + X (img n0, tile 0)
  for (int c = wid; c < NSTEP * 8; c += 4)
    gload_lds16(rsrc + (size_t)(c >> 3) * (U_ * 64) + (c & 7) * 1024 + lane * 16,
                (char*)lds_r + c * 1024);
  {
    const char* xs = (const char*)Xp +
        ((size_t)n0 * XROWS + wl * 128) * (XPR * 2);
#pragma unroll
    for (int c = 0; c < XWCH; ++c)
      gload_lds16(xs + c * 1024 + lane * 16, xdst + c * 1024);
  }
  asm volatile("s_waitcnt vmcnt(0)" ::: "memory");
  __builtin_amdgcn_s_barrier();        // the ONLY barrier: lds_r visibility

  const int fl = lane & 15;            // frag row (A: u) / col (B: l)
  const int fj = lane >> 4;            // k sub-chunk (8 shorts each)
  const int rfo = (wu * 64 + fl) * 32 + (fj << 3);
  const unsigned short* xb =
      (const unsigned short*)xdst + fl * XPR + (fj << 3);
  const int ug = fj << 2;

  float* Z = out + SZ_S + SZ_R;
  float pmax[4][4];                    // [ut][reg], per-image (flushed)
#pragma unroll
  for (int ut = 0; ut < 4; ++ut)
#pragma unroll
    for (int r = 0; r < 4; ++r) pmax[ut][r] = -INFINITY;

  f32x4 accA[4][8], accB[4][8];        // double accumulators (256 VGPR)
  uint4v xr[XWCH];                     // X reg-stage for next tile (28 VGPR)

  // paced store-group schedule: group g at step sgk[g] (R21-proven)
#define SGK(k) ((k)==1?0:(k)==2?1:(k)==4?2:(k)==5?3:(k)==7?4:(k)==9?5:   \
                (k)==10?6:(k)==12?7:-1)

#define ZERO(ACC)                                                            \
  {                                                                          \
    _Pragma("unroll")                                                        \
    for (int ut = 0; ut < 4; ++ut)                                           \
      _Pragma("unroll")                                                      \
      for (int lt = 0; lt < 8; ++lt)                                         \
        (ACC)[ut][lt] = (f32x4){0.f, 0.f, 0.f, 0.f};                         \
  }

#define KSTEP(K, ACC)                                                        \
  {                                                                          \
    short8 xfr[8], rfr[4];                                                   \
    const unsigned short* rb = lds_r + (K) * 4096 + rfo;                     \
    _Pragma("unroll")                                                        \
    for (int lt = 0; lt < 8; ++lt)                                           \
      xfr[lt] = *(const short8*)(xb + lt * (16 * XPR) + (K) * 32);           \
    _Pragma("unroll")                                                        \
    for (int ut = 0; ut < 4; ++ut)                                           \
      rfr[ut] = *(const short8*)(rb + ut * (16 * 32));                       \
    _Pragma("unroll")                                                        \
    for (int ut = 0; ut < 4; ++ut)                                           \
      _Pragma("unroll")                                                      \
      for (int lt = 0; lt < 8; ++lt)                                         \
        (ACC)[ut][lt] = __builtin_amdgcn_mfma_f32_16x16x32_bf16(             \
            rfr[ut], xfr[lt], (ACC)[ut][lt], 0, 0, 0);                       \
  }

  // in-bounds store of lt-group LT, tile TT (0..2) of image NN
#define STORE4(ACC, NN, TT, LT)                                              \
  {                                                                          \
    const int l = (TT) * 256 + wl * 128 + (LT) * 16 + fl;                    \
    float* zrow = Z + ((size_t)(NN) * LOUT + l) * U_ + u0 + wu * 64 + ug;    \
    _Pragma("unroll")                                                        \
    for (int ut = 0; ut < 4; ++ut) {                                         \
      f32x4 v = (ACC)[ut][LT];                                               \
      *(f32x4*)(zrow + ut * 16) = v;                                         \
      _Pragma("unroll")                                                      \
      for (int r = 0; r < 4; ++r) pmax[ut][r] = fmaxf(pmax[ut][r], v[r]);    \
    }                                                                        \
  }

  // clamped store of lt-group LT, tile 3 of image NN (uniform 32 stores;
  // OOB lanes go to the per-wave-private dump, distinct lines per lane)
#define STORE4C(ACC, NN, LT)                                                 \
  {                                                                          \
    const int l = 768 + wl * 128 + (LT) * 16 + fl;                           \
    const bool valid = (l < LOUT);                                           \
    float* zreal = Z + ((size_t)(NN) * LOUT + l) * U_ + u0 + wu * 64 + ug;   \
    float* zrow = valid ? zreal : wdump;                                     \
    _Pragma("unroll")                                                        \
    for (int ut = 0; ut < 4; ++ut) {                                         \
      f32x4 v = (ACC)[ut][LT];                                               \
      *(f32x4*)(zrow + ut * 16) = v;                                         \
      _Pragma("unroll")                                                      \
      for (int r = 0; r < 4; ++r)                                            \
        pmax[ut][r] = valid ? fmaxf(pmax[ut][r], v[r]) : pmax[ut][r];        \
    }                                                                        \
  }

#define XLOADS(NN, TT)                                                       \
  {                                                                          \
    const char* xs = (const char*)Xp +                                       \
        (((size_t)(NN) * XROWS + (TT) * 256 + wl * 128)) * (XPR * 2);        \
    _Pragma("unroll")                                                        \
    for (int c = 0; c < XWCH; ++c)                                           \
      xr[c] = *(const uint4v*)(xs + c * 1024 + lane * 16);                   \
  }

#define XWRITE()                                                             \
  {                                                                          \
    _Pragma("unroll")                                                        \
    for (int c = 0; c < XWCH; ++c)                                           \
      *(uint4v*)(xdst + c * 1024 + lane * 16) = xr[c];                       \
  }

  // per-image S flush: reduce pmax over fl lanes, atomics, reset
#define FLUSH(NN)                                                            \
  {                                                                          \
    _Pragma("unroll")                                                        \
    for (int off = 1; off < 16; off <<= 1)                                   \
      _Pragma("unroll")                                                      \
      for (int ut = 0; ut < 4; ++ut)                                         \
        _Pragma("unroll")                                                    \
        for (int r = 0; r < 4; ++r)                                          \
          pmax[ut][r] = fmaxf(pmax[ut][r], __shfl_xor(pmax[ut][r], off));    \
    if (fl == 0) {                                                           \
      float* Sp = out + (size_t)((NN) / F_) * U_ + u0 + wu * 64 + ug;        \
      _Pragma("unroll")                                                      \
      for (int ut = 0; ut < 4; ++ut)                                         \
        _Pragma("unroll")                                                    \
        for (int r = 0; r < 4; ++r)                                          \
          atomicMaxF(Sp + ut * 16 + r, pmax[ut][r]);                         \
    }                                                                        \
    _Pragma("unroll")                                                        \
    for (int ut = 0; ut < 4; ++ut)                                           \
      _Pragma("unroll")                                                      \
      for (int r = 0; r < 4; ++r) pmax[ut][r] = -INFINITY;                   \
  }

#pragma unroll 1
  for (int j = 0; j < 3; ++j) {
    const int n = n0 + (j << 7);

    // ---- tile (j,0): compute A; store prev image's t3 (accB, clamped)
    ZERO(accA)
    XLOADS(n, 1)
#pragma unroll
    for (int k = 0; k < NSTEP; ++k) {
      KSTEP(k, accA)
      if (j > 0 && SGK(k) >= 0) STORE4C(accB, n - 128, SGK(k))
    }
    if (j == 0) asm volatile("s_waitcnt vmcnt(0)" ::: "memory");
    else        asm volatile("s_waitcnt vmcnt(32)" ::: "memory");
    XWRITE()
    if (j > 0) FLUSH(n - 128)          // previous image's pmax complete

    // ---- tile (j,1): compute B; store (n, t0) from accA
    ZERO(accB)
    XLOADS(n, 2)
#pragma unroll
    for (int k = 0; k < NSTEP; ++k) {
      KSTEP(k, accB)
      if (SGK(k) >= 0) STORE4(accA, n, 0, SGK(k))
    }
    asm volatile("s_waitcnt vmcnt(32)" ::: "memory");
    XWRITE()

    // ---- tile (j,2): compute A; store (n, t1) from accB
    ZERO(accA)
    XLOADS(n, 3)
#pragma unroll
    for (int k = 0; k < NSTEP; ++k) {
      KSTEP(k, accA)
      if (SGK(k) >= 0) STORE4(accB, n, 1, SGK(k))
    }
    asm volatile("s_waitcnt vmcnt(32)" ::: "memory");
    XWRITE()

    // ---- tile (j,3): compute B; store (n, t2) from accA
    ZERO(accB)
    if (j < 2) XLOADS(n + 128, 0)
#pragma unroll
    for (int k = 0; k < NSTEP; ++k) {
      KSTEP(k, accB)
      if (SGK(k) >= 0) STORE4(accA, n, 2, SGK(k))
    }
    if (j < 2) {
      asm volatile("s_waitcnt vmcnt(32)" ::: "memory");
      XWRITE()
    }
  }

  // ---- final tail: store (n0+256, t3) from accB (guarded)
#pragma unroll
  for (int lt = 0; lt < 8; ++lt) {
    const int l = 768 + wl * 128 + lt * 16 + fl;
    if (l < LOUT) {
      float* zrow = Z + ((size_t)(n0 + 256) * LOUT + l) * U_ + u0 + wu * 64 + ug;
#pragma unroll
      for (int ut = 0; ut < 4; ++ut) {
        f32x4 v = accB[ut][lt];
        *(f32x4*)(zrow + ut * 16) = v;
#pragma unroll
        for (int r = 0; r < 4; ++r) pmax[ut][r] = fmaxf(pmax[ut][r], v[r]);
      }
    }
  }
  FLUSH(n0 + 256)

#undef SGK
#undef ZERO
#undef KSTEP
#undef STORE4
#undef STORE4C
#undef XLOADS
#undef XWRITE
#undef FLUSH
}

extern "C" void kernel_launch(void* const* d_in, const int* in_sizes, int n_in,
                              void* d_out, int out_size, void* d_ws, size_t ws_size,
                              hipStream_t stream) {
  const float* X       = (const float*)d_in[0];
  const float* P_logit = (const float*)d_in[1];
  const float* Q       = (const float*)d_in[2];
  float* out = (float*)d_out;

  unsigned short* Rt = (unsigned short*)d_ws;            // 240 KB
  unsigned short* Xp = (unsigned short*)((char*)d_ws + 262144);
  const size_t xp_bytes = (size_t)NIMG * XROWS * XPR * 2;  // ~18.6 MB
  // dump: 64 hashed block-slots x 4 waves x 16 KB = 4 MB (per-wave private)
  float* dump = (float*)((char*)d_ws + 262144 + xp_bytes);

  int xthreads = NIMG * XROWS * 12;
  hipLaunchKernelGGL(xprep_kernel, dim3((xthreads + 255) / 256), dim3(256),
                     0, stream, X, P_logit, Q, out, Rt, (unsigned int*)Xp);
  dim3 grid(2, 1, 128);    // u-halves x base-images; 3 images per block
  hipLaunchKernelGGL(conv_kernel, grid, dim3(256), 0, stream,
                     Xp, Rt, out, dump);
}

// Round 23
// 120.039 us; speedup vs baseline: 2.0872x; 2.0872x over previous
//
#include <hip/hip_runtime.h>
#include <hip/hip_bf16.h>
#include <math.h>

// Problem constants
#define T_ 4
#define N_ 16
#define F_ 6
#define L_ 1024
#define A_ 21
#define K_ 20
#define U_ 256
#define LOUT 1005            // L - K + 1
#define NIMG 384             // T*N*F
#define SZ_S (T_*N_*U_)      // 16384
#define SZ_R (K_*A_*U_)      // 107520

// Packed-X geometry: row stride 24 shorts (48 B). For output row l, contraction
// slot c maps to tap=c/24, col=c%24 (independent of l). Valid slots 0..476 ->
// 15 K-steps of 32 (480); cols 21..23 zero in R.
#define XPR 24               // shorts per packed row
#define XROWS 1056           // padded rows per image
#define NSTEP 15             // K-steps of 32 slots
#define XWCH 7               // private X chunks of 1 KB per wave (149 rows)

typedef __attribute__((ext_vector_type(8))) short short8;   // 8 bf16 (4 VGPR)
typedef __attribute__((ext_vector_type(4))) float f32x4;    // 4 f32 acc
typedef __attribute__((ext_vector_type(4))) unsigned int uint4v;

__device__ __forceinline__ unsigned short f2bf(float f) {
  unsigned int u = __float_as_uint(f);
  u += 0x7FFFu + ((u >> 16) & 1u);   // round to nearest even
  return (unsigned short)(u >> 16);
}

__device__ __forceinline__ void atomicMaxF(float* addr, float val) {
  if (val >= 0.f) atomicMax((int*)addr, __float_as_int(val));
  else            atomicMin((unsigned int*)addr, __float_as_uint(val));
}

// Async global->LDS, 16B per lane. LDS dest is wave-uniform base + lane*16.
__device__ __forceinline__ void gload_lds16(const void* g, void* l) {
  __builtin_amdgcn_global_load_lds(
      (const __attribute__((address_space(1))) void*)g,
      (__attribute__((address_space(3))) void*)l, 16, 0, 0);
}

// Merged pre-pass (single launch): S init, R (fp32 exact) -> d_out,
// Rt = bf16 R in slot order with a BOTH-SIDES XOR SWIZZLE (G21): within each
// 64 B u-row, 16 B slot-group s4 is stored at position s4 ^ ((u>>1)&3).
// global_load_lds then copies linearly and the conv ds_read XORs the same
// mask -> R fragment reads become 2-way bank-spread (free) instead of the
// 8-way conflict measured in R22 (SQ_LDS_BANK_CONFLICT 8.8M/dispatch).
// X fp32 -> packed bf16 Xp unchanged.
__global__ void xprep_kernel(const float* __restrict__ X,
                             const float* __restrict__ P_logit,
                             const float* __restrict__ Q,
                             float* __restrict__ out,
                             unsigned short* __restrict__ Rt,
                             unsigned int* __restrict__ Xp32) {
  int t = blockIdx.x * blockDim.x + threadIdx.x;
  if (t < SZ_S) out[t] = -INFINITY;            // S init for atomic max

  if (t < K_ * U_) {                           // R / Rt part
    int k = t / U_;
    int u = t - k * U_;
    const float* pl = P_logit + (size_t)k * A_ * U_ + u;
    float v[A_];
    float m = -INFINITY;
#pragma unroll
    for (int a = 0; a < A_; ++a) { v[a] = pl[(size_t)a * U_]; m = fmaxf(m, v[a]); }
    float s = 0.f;
#pragma unroll
    for (int a = 0; a < A_; ++a) { v[a] = expf(v[a] - m); s += v[a]; }
    float qs = 0.f;
#pragma unroll
    for (int a = 0; a < A_; ++a) qs += Q[a];
    float eps = qs * (1.0f / A_);
    float invs = 1.f / s;
    float* Rout = out + SZ_S;
    const int um = (u >> 1) & 3;               // swizzle mask for this u-row
#pragma unroll
    for (int a = 0; a < XPR; ++a) {
      unsigned short bv = 0;
      if (a < A_) {
        float r = logf(fmaxf(v[a] * invs / Q[a], eps));
        Rout[(size_t)(k * A_ + a) * U_ + u] = r;
        bv = f2bf(r);
      }
      int sl = k * XPR + a;
      int w = sl & 31;                         // slot within 32-slot step row
      int widx = (((w >> 3) ^ um) << 3) | (w & 7);   // swizzled position
      Rt[(size_t)(sl >> 5) * (U_ * 32) + u * 32 + widx] = bv;
    }
  }

  if (t < NIMG * XROWS * 12) {                 // X conversion part
    int w  = t % 12;
    int rl = t / 12;               // n*XROWS + row
    int row = rl % XROWS;
    int n   = rl / XROWS;
    int c0 = w * 2;
    float v0 = 0.f, v1 = 0.f;
    if (row < L_) {
      const float* xr = X + ((size_t)n * L_ + row) * A_;
      if (c0 < A_)     v0 = xr[c0];
      if (c0 + 1 < A_) v1 = xr[c0 + 1];
    }
    unsigned int o = (unsigned int)f2bf(v0) | ((unsigned int)f2bf(v1) << 16);
    Xp32[(size_t)rl * 12 + w] = o;
  }
}

// Conv as one GEMM: M=u (A=R slots), N=l (B=packed-X window), K=480 (15 steps).
// R23 = R21 (best, 120.1 µs) with ONE delta: the R fragment read address XORs
// the (u>>1)&3 slot-group swizzle baked into Rt by xprep (both-sides, G21) --
// removes the 8-way LDS bank conflict on R reads (R22 PMC: 8.8M conflict cyc
// per dispatch ~ 15% of runtime). Everything else identical: persistent R
// (120 KB LDS, staged once/block), wave-private X buffers, double accumulators
// with paced stores at steps {1,2,4,5,7,9,10,12}, T14 reg-staged X, zero
// barriers after the prologue. 4 waves (2u x 2l), wave 64u x 128l.
__global__ __launch_bounds__(256, 1) void conv_kernel(
    const unsigned short* __restrict__ Xp,
    const unsigned short* __restrict__ Rt,
    float* __restrict__ out) {
  __shared__ __align__(16) unsigned short lds_r[NSTEP * 4096];     // 120 KB
  __shared__ __align__(16) unsigned short lds_xp[4][XWCH * 512];   // 28 KB

  const int n  = blockIdx.z;
  const int u0 = blockIdx.x * 128;
  const int wid  = threadIdx.x >> 6;
  const int lane = threadIdx.x & 63;
  const int wl = wid >> 1;             // wave l position (0..1), 128 l each
  const int wu = wid & 1;              // wave u position (0..1), 64 u each

  // wave's private X source: rows t*256 + wl*128 .. +149 (halo 19 incl.)
  const char* xsrc = (const char*)Xp +
      ((size_t)n * XROWS + wl * 128) * (XPR * 2);
  const char* rsrc = (const char*)Rt + (size_t)u0 * 64;   // block's u-half
  char* xdst = (char*)&lds_xp[wid][0];

  // ---- prologue: ALL of R (30 chunks/wave, shared) + private X tile 0
  for (int c = wid; c < NSTEP * 8; c += 4)
    gload_lds16(rsrc + (size_t)(c >> 3) * (U_ * 64) + (c & 7) * 1024 + lane * 16,
                (char*)lds_r + c * 1024);
#pragma unroll
  for (int c = 0; c < XWCH; ++c)
    gload_lds16(xsrc + c * 1024 + lane * 16, xdst + c * 1024);
  asm volatile("s_waitcnt vmcnt(0)" ::: "memory");
  __builtin_amdgcn_s_barrier();        // the ONLY barrier: lds_r visibility

  const int fl = lane & 15;            // frag row (A: u) / col (B: l)
  const int fj = lane >> 4;            // k sub-chunk (8 shorts each)
  // R read offset with the baked-in swizzle: slot-group fj ^ ((u>>1)&3);
  // (u>>1)&3 == (fl>>1)&3 (ut*16, wu*64 don't affect bits 1-2).
  const int rfo = (wu * 64 + fl) * 32 + ((fj ^ ((fl >> 1) & 3)) << 3);
  const unsigned short* xb =
      (const unsigned short*)xdst + fl * XPR + (fj << 3);
  const int ug = fj << 2;

  float* Z = out + SZ_S + SZ_R;
  float pmax[4][4];                    // [ut][reg], carried across all tiles
#pragma unroll
  for (int ut = 0; ut < 4; ++ut)
#pragma unroll
    for (int r = 0; r < 4; ++r) pmax[ut][r] = -INFINITY;

  f32x4 accA[4][8], accB[4][8];        // double accumulators (256 VGPR)
  uint4v xr[XWCH];                     // X reg-stage for next tile (28 VGPR)

  // paced store-group schedule: group g at step sgk[g]
#define SGK(k) ((k)==1?0:(k)==2?1:(k)==4?2:(k)==5?3:(k)==7?4:(k)==9?5:   \
                (k)==10?6:(k)==12?7:-1)

#define ZERO(ACC)                                                            \
  {                                                                          \
    _Pragma("unroll")                                                        \
    for (int ut = 0; ut < 4; ++ut)                                           \
      _Pragma("unroll")                                                      \
      for (int lt = 0; lt < 8; ++lt)                                         \
        (ACC)[ut][lt] = (f32x4){0.f, 0.f, 0.f, 0.f};                         \
  }

#define KSTEP(K, ACC)                                                        \
  {                                                                          \
    short8 xfr[8], rfr[4];                                                   \
    const unsigned short* rb = lds_r + (K) * 4096 + rfo;                     \
    _Pragma("unroll")                                                        \
    for (int lt = 0; lt < 8; ++lt)                                           \
      xfr[lt] = *(const short8*)(xb + lt * (16 * XPR) + (K) * 32);           \
    _Pragma("unroll")                                                        \
    for (int ut = 0; ut < 4; ++ut)                                           \
      rfr[ut] = *(const short8*)(rb + ut * (16 * 32));                       \
    _Pragma("unroll")                                                        \
    for (int ut = 0; ut < 4; ++ut)                                           \
      _Pragma("unroll")                                                      \
      for (int lt = 0; lt < 8; ++lt)                                         \
        (ACC)[ut][lt] = __builtin_amdgcn_mfma_f32_16x16x32_bf16(             \
            rfr[ut], xfr[lt], (ACC)[ut][lt], 0, 0, 0);                       \
  }

  // store lt-group LT of tile TT from ACC (tiles 0..2: always in-bounds)
#define STORE4(ACC, TT, LT)                                                  \
  {                                                                          \
    const int l = (TT) * 256 + wl * 128 + (LT) * 16 + fl;                    \
    float* zrow = Z + ((size_t)n * LOUT + l) * U_ + u0 + wu * 64 + ug;       \
    _Pragma("unroll")                                                        \
    for (int ut = 0; ut < 4; ++ut) {                                         \
      f32x4 v = (ACC)[ut][LT];                                               \
      *(f32x4*)(zrow + ut * 16) = v;                                         \
      _Pragma("unroll")                                                      \
      for (int r = 0; r < 4; ++r) pmax[ut][r] = fmaxf(pmax[ut][r], v[r]);    \
    }                                                                        \
  }

#define XLOADS(T1)                                                           \
  {                                                                          \
    const char* xs = xsrc + (size_t)(T1) * (256 * XPR * 2);                  \
    _Pragma("unroll")                                                        \
    for (int c = 0; c < XWCH; ++c)                                           \
      xr[c] = *(const uint4v*)(xs + c * 1024 + lane * 16);                   \
  }

#define XWRITE()                                                             \
  {                                                                          \
    _Pragma("unroll")                                                        \
    for (int c = 0; c < XWCH; ++c)                                           \
      *(uint4v*)(xdst + c * 1024 + lane * 16) = xr[c];                       \
  }

  // ---- tile 0: compute accA; reg-load X1 (issued before any stores)
  ZERO(accA)
  XLOADS(1)
#pragma unroll
  for (int k = 0; k < NSTEP; ++k) KSTEP(k, accA)
  asm volatile("s_waitcnt vmcnt(0)" ::: "memory");   // xr ready (only loads)
  XWRITE()

  // ---- tile 1: compute accB; paced stores of tile 0; reg-load X2
  ZERO(accB)
  XLOADS(2)
#pragma unroll
  for (int k = 0; k < NSTEP; ++k) {
    KSTEP(k, accB)
    if (SGK(k) >= 0) STORE4(accA, 0, SGK(k))
  }
  asm volatile("s_waitcnt vmcnt(32)" ::: "memory");  // retire 7 oldest = xloads
  XWRITE()

  // ---- tile 2: compute accA; paced stores of tile 1; reg-load X3
  ZERO(accA)
  XLOADS(3)
#pragma unroll
  for (int k = 0; k < NSTEP; ++k) {
    KSTEP(k, accA)
    if (SGK(k) >= 0) STORE4(accB, 1, SGK(k))
  }
  asm volatile("s_waitcnt vmcnt(32)" ::: "memory");
  XWRITE()

  // ---- tile 3: compute accB; paced stores of tile 2
  ZERO(accB)
#pragma unroll
  for (int k = 0; k < NSTEP; ++k) {
    KSTEP(k, accB)
    if (SGK(k) >= 0) STORE4(accA, 2, SGK(k))
  }

  // ---- tail: store tile 3 (guarded: rows 768..1023 vs LOUT=1005)
#pragma unroll
  for (int lt = 0; lt < 8; ++lt) {
    const int l = 768 + wl * 128 + lt * 16 + fl;
    if (l < LOUT) {
      float* zrow = Z + ((size_t)n * LOUT + l) * U_ + u0 + wu * 64 + ug;
#pragma unroll
      for (int ut = 0; ut < 4; ++ut) {
        f32x4 v = accB[ut][lt];
        *(f32x4*)(zrow + ut * 16) = v;
#pragma unroll
        for (int r = 0; r < 4; ++r) pmax[ut][r] = fmaxf(pmax[ut][r], v[r]);
      }
    }
  }

#undef SGK
#undef ZERO
#undef KSTEP
#undef STORE4
#undef XLOADS
#undef XWRITE

  // ---- S epilogue: reduce over the frag's 16 cols (fl), atomics once.
#pragma unroll
  for (int off = 1; off < 16; off <<= 1)
#pragma unroll
    for (int ut = 0; ut < 4; ++ut)
#pragma unroll
      for (int r = 0; r < 4; ++r)
        pmax[ut][r] = fmaxf(pmax[ut][r], __shfl_xor(pmax[ut][r], off));

  if (fl == 0) {                       // lanes fj*16
    const int tn = n / F_;
    float* Sp = out + (size_t)tn * U_ + u0 + wu * 64 + ug;
#pragma unroll
    for (int ut = 0; ut < 4; ++ut)
#pragma unroll
      for (int r = 0; r < 4; ++r)
        atomicMaxF(Sp + ut * 16 + r, pmax[ut][r]);
  }
}

extern "C" void kernel_launch(void* const* d_in, const int* in_sizes, int n_in,
                              void* d_out, int out_size, void* d_ws, size_t ws_size,
                              hipStream_t stream) {
  const float* X       = (const float*)d_in[0];
  const float* P_logit = (const float*)d_in[1];
  const float* Q       = (const float*)d_in[2];
  float* out = (float*)d_out;

  unsigned short* Rt = (unsigned short*)d_ws;            // 240 KB
  unsigned short* Xp = (unsigned short*)((char*)d_ws + 262144);
  // Xp: NIMG*XROWS*24 shorts (~18.6 MB). All staged rows <= 1045 < 1056:
  // fully in-bounds; no over-read.

  int xthreads = NIMG * XROWS * 12;
  hipLaunchKernelGGL(xprep_kernel, dim3((xthreads + 255) / 256), dim3(256),
                     0, stream, X, P_logit, Q, out, Rt, (unsigned int*)Xp);
  dim3 grid(2, 1, NIMG);   // u-tiles, -, images (4 l-tiles looped in-kernel)
  hipLaunchKernelGGL(conv_kernel, grid, dim3(256), 0, stream, Xp, Rt, out);
}